// Round 8
// baseline (170.903 us; speedup 1.0000x reference)
//
#include <hip/hip_runtime.h>
#include <math.h>

#define D  48
#define DQ 12        // D/4
#define SPAN 128     // nodes per bucket
#define SHIFT 7      // log2(SPAN)
#define PCH  4096    // edges per hist/partition block
#define PTH  512     // threads for hist/part
#define NGRP 21

constexpr float F_EPS   = 1e-15f;
constexpr float MAXNORM = 1.0f - 1e-5f;

__device__ __forceinline__ float artanh_c(float x) {
    x = fminf(x, 1.0f - 1e-7f);
    x = fmaxf(x, -1.0f + 1e-7f);
    return atanhf(x);
}

__device__ __forceinline__ float clampabs(float x) {
    return (x >= 0.0f) ? fmaxf(x, 1e-10f) : fminf(x, -1e-10f);
}

__device__ __forceinline__ unsigned short f2bf(float f) {
    unsigned u = __float_as_uint(f);
    u += 0x7FFFu + ((u >> 16) & 1u);
    return (unsigned short)(u >> 16);
}

__device__ __forceinline__ float bf2f(unsigned short u) {
    return __uint_as_float(((unsigned)u) << 16);
}

// ---------- per-node gamma + zero bucket histogram ----------
__global__ void k_gamma(const float* __restrict__ x, float* __restrict__ gam,
                        int* __restrict__ ghist, int n, int nb)
{
    int i = blockIdx.x * blockDim.x + threadIdx.x;
    if (i < nb) ghist[i] = 0;
    if (i >= n) return;
    const float4* xr = reinterpret_cast<const float4*>(x) + (size_t)i * DQ;
    float s = 0.0f;
#pragma unroll
    for (int q = 0; q < DQ; ++q) {
        float4 v = xr[q];
        s += v.x * v.x + v.y * v.y + v.z * v.z + v.w * v.w;
    }
    gam[i] = 2.0f / fmaxf(1.0f - s, F_EPS);
}

// ---------- bucket histogram (LDS-staged, unrolled) ----------
__global__ __launch_bounds__(PTH) void k_hist(const int* __restrict__ dst,
                                              int* __restrict__ ghist, int E, int nb)
{
    __shared__ int h[1024];
    int t = threadIdx.x;
    for (int i = t; i < 1024; i += PTH) h[i] = 0;
    __syncthreads();
    int base = blockIdx.x * PCH;
#pragma unroll
    for (int k = 0; k < PCH / PTH; ++k) {
        int i = base + k * PTH + t;
        if (i < E) {
            unsigned b = ((unsigned)dst[i]) >> SHIFT;
            if (b < 1024u) atomicAdd(&h[b], 1);
        }
    }
    __syncthreads();
    for (int i = t; i < nb; i += PTH) {
        int c = h[i];
        if (c) atomicAdd(&ghist[i], c);
    }
}

// ---------- exclusive scan of bucket counts (single block, nb <= 1024) ----------
__global__ __launch_bounds__(1024) void k_scanb(const int* __restrict__ ghist,
                                                int* __restrict__ gstart,
                                                int* __restrict__ gcur, int nb, int E)
{
    __shared__ int sh[1024];
    int t = threadIdx.x;
    int v = (t < nb) ? ghist[t] : 0;
    sh[t] = v;
    __syncthreads();
    for (int off = 1; off < 1024; off <<= 1) {
        int a = sh[t];
        int b = (t >= off) ? sh[t - off] : 0;
        __syncthreads();
        sh[t] = a + b;
        __syncthreads();
    }
    if (t < nb) { int s = sh[t] - v; gstart[t] = s; gcur[t] = s; }
    if (t == 0) gstart[nb] = E;
}

// ---------- partition edges into bucket segments ----------
__global__ __launch_bounds__(PTH) void k_part(const int* __restrict__ src,
                                              const int* __restrict__ dst,
                                              const float* __restrict__ w,
                                              int* __restrict__ gcur,
                                              int2* __restrict__ seg, int E, int nb)
{
    __shared__ int hist[1024];
    __shared__ int base_[1024];
    __shared__ int lcur[1024];
    int t = threadIdx.x;
    for (int i = t; i < 1024; i += PTH) { hist[i] = 0; base_[i] = 0; lcur[i] = 0; }
    __syncthreads();
    int b0 = blockIdx.x * PCH;
#pragma unroll
    for (int k = 0; k < PCH / PTH; ++k) {
        int i = b0 + k * PTH + t;
        if (i < E) {
            unsigned b = ((unsigned)dst[i]) >> SHIFT;
            if (b < 1024u) atomicAdd(&hist[b], 1);
        }
    }
    __syncthreads();
    for (int i = t; i < nb; i += PTH) {
        int c = hist[i];
        if (c) base_[i] = atomicAdd(&gcur[i], c);
    }
    __syncthreads();
#pragma unroll
    for (int k = 0; k < PCH / PTH; ++k) {
        int i = b0 + k * PTH + t;
        if (i < E) {
            int d = dst[i];
            unsigned b = ((unsigned)d) >> SHIFT;
            if (b < 1024u) {
                int pos = base_[b] + atomicAdd(&lcur[b], 1);
                if (pos >= 0 && pos < E) {
                    int2 r;
                    r.x = ((d & (SPAN - 1)) << 24) | (src[i] & 0xFFFFFF);
                    r.y = __float_as_int(w[i]);
                    seg[pos] = r;
                }
            }
        }
    }
}

// ---------- per-bucket LDS counting sort -> exact per-node order + starts ----------
__global__ __launch_bounds__(256) void k_sortb(
    const int2* __restrict__ seg, const int* __restrict__ gstart,
    int* __restrict__ starts, int2* __restrict__ seg2, int n, int E)
{
    __shared__ int hist[SPAN];
    __shared__ int sb[SPAN];
    __shared__ int cur[SPAN];
    int b = blockIdx.x;
    int t = threadIdx.x;
    if (b == 0 && t == 0) starts[n] = E;
    int segL = gstart[b], segR = gstart[b + 1];
    if (segL < 0) segL = 0;
    if (segR > E) segR = E;
    if (t < SPAN) hist[t] = 0;
    __syncthreads();
    {
        int j = segL + t;
        for (; j + 768 < segR; j += 1024) {
            unsigned d0 = ((unsigned)seg[j      ].x) >> 24;
            unsigned d1 = ((unsigned)seg[j + 256].x) >> 24;
            unsigned d2 = ((unsigned)seg[j + 512].x) >> 24;
            unsigned d3 = ((unsigned)seg[j + 768].x) >> 24;
            atomicAdd(&hist[d0], 1);
            atomicAdd(&hist[d1], 1);
            atomicAdd(&hist[d2], 1);
            atomicAdd(&hist[d3], 1);
        }
        for (; j < segR; j += 256) {
            unsigned dl = ((unsigned)seg[j].x) >> 24;
            atomicAdd(&hist[dl], 1);
        }
    }
    __syncthreads();
    if (t < SPAN) sb[t] = hist[t];
    __syncthreads();
    for (int off = 1; off < SPAN; off <<= 1) {
        int a = 0;
        if (t < SPAN) { a = sb[t]; if (t >= off) a += sb[t - off]; }
        __syncthreads();
        if (t < SPAN) sb[t] = a;
        __syncthreads();
    }
    if (t < SPAN) {
        int ls = sb[t] - hist[t];
        cur[t] = segL + ls;
        int node = b * SPAN + t;
        if (node < n) starts[node] = segL + ls;
    }
    __syncthreads();
    {
        int j = segL + t;
        for (; j + 768 < segR; j += 1024) {
            int2 r0 = seg[j      ];
            int2 r1 = seg[j + 256];
            int2 r2 = seg[j + 512];
            int2 r3 = seg[j + 768];
            int p0 = atomicAdd(&cur[((unsigned)r0.x) >> 24], 1);
            int p1 = atomicAdd(&cur[((unsigned)r1.x) >> 24], 1);
            int p2 = atomicAdd(&cur[((unsigned)r2.x) >> 24], 1);
            int p3 = atomicAdd(&cur[((unsigned)r3.x) >> 24], 1);
            if (p0 >= 0 && p0 < E) seg2[p0] = make_int2(r0.x & 0xFFFFFF, r0.y);
            if (p1 >= 0 && p1 < E) seg2[p1] = make_int2(r1.x & 0xFFFFFF, r1.y);
            if (p2 >= 0 && p2 < E) seg2[p2] = make_int2(r2.x & 0xFFFFFF, r2.y);
            if (p3 >= 0 && p3 < E) seg2[p3] = make_int2(r3.x & 0xFFFFFF, r3.y);
        }
        for (; j < segR; j += 256) {
            int2 r = seg[j];
            int pos = atomicAdd(&cur[((unsigned)r.x) >> 24], 1);
            if (pos >= 0 && pos < E) seg2[pos] = make_int2(r.x & 0xFFFFFF, r.y);
        }
    }
}

// ---------- precompute ybf[s] = bf16(gam[s] * x[s]) into dead seg buffer ----------
__global__ __launch_bounds__(256) void k_prep(const float* __restrict__ x,
                                              const float* __restrict__ gam,
                                              ushort4* __restrict__ ybf, int n)
{
    long long t = (long long)blockIdx.x * blockDim.x + threadIdx.x;
    int node = (int)(t / DQ);
    if (node >= n) return;
    int part = (int)(t % DQ);
    float g = gam[node];
    float4 v = reinterpret_cast<const float4*>(x)[(size_t)node * DQ + part];
    ushort4 o;
    o.x = f2bf(v.x * g);
    o.y = f2bf(v.y * g);
    o.z = f2bf(v.z * g);
    o.w = f2bf(v.w * g);
    ybf[(size_t)node * DQ + part] = o;
}

// ---------- gather-side segment reduction: 12 lanes per node, bf16 rows ----------
__global__ __launch_bounds__(256) void k_gather(
    const ushort4* __restrict__ ybf, const float* __restrict__ gam,
    const int* __restrict__ starts,
    const int2* __restrict__ srec,
    float* __restrict__ num, float* __restrict__ den, int n, int E)
{
    long long t = (long long)blockIdx.x * blockDim.x + threadIdx.x;
    int node = (int)(t / DQ);
    if (node >= n) return;
    int part = (int)(t % DQ);
    int j0 = starts[node], j1 = starts[node + 1];
    if (j0 < 0) j0 = 0;
    if (j1 > E) j1 = E;
    float4 acc = make_float4(0.f, 0.f, 0.f, 0.f);
    float dacc = 0.f;
    int j = j0;
    for (; j + 1 < j1; j += 2) {
        int2 r0 = srec[j];
        int2 r1 = srec[j + 1];
        int s0 = r0.x, s1 = r1.x;
        float w0 = __int_as_float(r0.y);
        float w1 = __int_as_float(r1.y);
        bool v0 = (s0 >= 0 && s0 < n), v1 = (s1 >= 0 && s1 < n);
        float g0 = v0 ? gam[s0] : 1.f;
        float g1 = v1 ? gam[s1] : 1.f;
        ushort4 a0 = v0 ? ybf[(size_t)s0 * DQ + part] : make_ushort4(0,0,0,0);
        ushort4 a1 = v1 ? ybf[(size_t)s1 * DQ + part] : make_ushort4(0,0,0,0);
        acc.x = fmaf(w0, bf2f(a0.x), acc.x);
        acc.y = fmaf(w0, bf2f(a0.y), acc.y);
        acc.z = fmaf(w0, bf2f(a0.z), acc.z);
        acc.w = fmaf(w0, bf2f(a0.w), acc.w);
        acc.x = fmaf(w1, bf2f(a1.x), acc.x);
        acc.y = fmaf(w1, bf2f(a1.y), acc.y);
        acc.z = fmaf(w1, bf2f(a1.z), acc.z);
        acc.w = fmaf(w1, bf2f(a1.w), acc.w);
        dacc += fabsf(w0) * (g0 - 1.0f) + fabsf(w1) * (g1 - 1.0f);
    }
    if (j < j1) {
        int2 r0 = srec[j];
        int s0 = r0.x;
        float w0 = __int_as_float(r0.y);
        bool v0 = (s0 >= 0 && s0 < n);
        float g0 = v0 ? gam[s0] : 1.f;
        ushort4 a0 = v0 ? ybf[(size_t)s0 * DQ + part] : make_ushort4(0,0,0,0);
        acc.x = fmaf(w0, bf2f(a0.x), acc.x);
        acc.y = fmaf(w0, bf2f(a0.y), acc.y);
        acc.z = fmaf(w0, bf2f(a0.z), acc.z);
        acc.w = fmaf(w0, bf2f(a0.w), acc.w);
        dacc += fabsf(w0) * (g0 - 1.0f);
    }
    reinterpret_cast<float4*>(num)[(size_t)node * DQ + part] = acc;
    if (part == 0) den[node] = dacc;
}

// ---------- fallback: atomic edge scatter ----------
__global__ void k_init_atomic(float* __restrict__ den, float* __restrict__ num, int n)
{
    int i = blockIdx.x * blockDim.x + threadIdx.x;
    if (i >= n) return;
    den[i] = 0.0f;
    float4* nr = reinterpret_cast<float4*>(num) + (size_t)i * DQ;
    float4 z = make_float4(0.f, 0.f, 0.f, 0.f);
#pragma unroll
    for (int q = 0; q < DQ; ++q) nr[q] = z;
}

__global__ void k_edge_atomic(const float* __restrict__ x, const float* __restrict__ gam,
                              const int* __restrict__ src, const int* __restrict__ dst,
                              const float* __restrict__ w,
                              float* __restrict__ num, float* __restrict__ den, int E)
{
    long long t = (long long)blockIdx.x * blockDim.x + threadIdx.x;
    int e = (int)(t / DQ);
    if (e >= E) return;
    int part = (int)(t % DQ);
    int s = src[e];
    int d = dst[e];
    float we = w[e];
    float g  = gam[s];
    float4 xv = reinterpret_cast<const float4*>(x)[(size_t)s * DQ + part];
    float c = we * g;
    float* np_ = num + (size_t)d * D + part * 4;
    atomicAdd(np_ + 0, c * xv.x);
    atomicAdd(np_ + 1, c * xv.y);
    atomicAdd(np_ + 2, c * xv.z);
    atomicAdd(np_ + 3, c * xv.w);
    if (part == 0) atomicAdd(den + d, fabsf(we) * (g - 1.0f));
}

// mobius_scalar_mul(0.5, v) followed by _project, in place.
__device__ __forceinline__ void half_mul_project(float* v)
{
    float s = 0.f;
#pragma unroll
    for (int k = 0; k < D; ++k) s += v[k] * v[k];
    float nrm = sqrtf(s);
    float ncl = fmaxf(nrm, F_EPS);
    float t   = tanhf(0.5f * artanh_c(ncl));
    float sc  = t / ncl;
    float rn  = nrm * sc;
    if (rn > MAXNORM) sc *= MAXNORM / fmaxf(rn, F_EPS);
#pragma unroll
    for (int k = 0; k < D; ++k) v[k] *= sc;
}

__global__ __launch_bounds__(256) void k_node(
    float* __restrict__ out,
    const float* __restrict__ den,
    const float* __restrict__ h_init,
    const float* __restrict__ Wm,
    const float* __restrict__ bias, int n)
{
    __shared__ float Ws[D * D];
    __shared__ float bs[D];
    for (int k = threadIdx.x; k < D * D; k += blockDim.x) Ws[k] = Wm[k];
    if (threadIdx.x < D) bs[threadIdx.x] = bias[threadIdx.x];
    __syncthreads();

    int i = blockIdx.x * blockDim.x + threadIdx.x;
    if (i >= n) return;

    float a[D];
    {
        const float4* nr = reinterpret_cast<const float4*>(out) + (size_t)i * DQ;
        float dinv = 1.0f / clampabs(den[i]);
#pragma unroll
        for (int q = 0; q < DQ; ++q) {
            float4 v = nr[q];
            a[q * 4 + 0] = v.x * dinv;
            a[q * 4 + 1] = v.y * dinv;
            a[q * 4 + 2] = v.z * dinv;
            a[q * 4 + 3] = v.w * dinv;
        }
    }
    half_mul_project(a);

    {
        float b[D];
        const float4* hr = reinterpret_cast<const float4*>(h_init) + (size_t)i * DQ;
#pragma unroll
        for (int q = 0; q < DQ; ++q) {
            float4 v = hr[q];
            b[q * 4 + 0] = v.x; b[q * 4 + 1] = v.y;
            b[q * 4 + 2] = v.z; b[q * 4 + 3] = v.w;
        }
        float sa = 0.f, sb = 0.f;
#pragma unroll
        for (int k = 0; k < D; ++k) { sa += a[k] * a[k]; sb += b[k] * b[k]; }
        float ga = 2.0f / fmaxf(1.0f - sa, F_EPS);
        float gb = 2.0f / fmaxf(1.0f - sb, F_EPS);
        const float wa = 0.9f, wb = 0.1f;
        float dinv = 1.0f / clampabs(wa * (ga - 1.0f) + wb * (gb - 1.0f));
        float ca = wa * ga * dinv, cb = wb * gb * dinv;
#pragma unroll
        for (int k = 0; k < D; ++k) a[k] = ca * a[k] + cb * b[k];
        half_mul_project(a);
    }

    float mx[D];
    {
        float sa2 = 0.f;
#pragma unroll
        for (int k = 0; k < D; ++k) sa2 += a[k] * a[k];
        float xn = fmaxf(sqrtf(sa2), F_EPS);
        float smx = 0.f;
        for (int j = 0; j < D; ++j) {
            float acc = 0.f;
#pragma unroll
            for (int k = 0; k < D; ++k) acc = fmaf(Ws[j * D + k], a[k], acc);
            mx[j] = acc;
            smx += acc * acc;
        }
        float mxnr = sqrtf(smx);
        float mxn = fmaxf(mxnr, F_EPS);
        float tt = tanhf((mxn / xn) * artanh_c(xn));
        float sc = tt / mxn;
        float rn = mxnr * sc;
        if (rn > MAXNORM) sc *= MAXNORM / fmaxf(rn, F_EPS);
#pragma unroll
        for (int j = 0; j < D; ++j) mx[j] *= sc;
    }

    {
        float bn2 = 0.f;
#pragma unroll
        for (int k = 0; k < D; ++k) bn2 += bs[k] * bs[k];
        float bn  = fmaxf(sqrtf(bn2), F_EPS);
        float tb  = tanhf(bn);
        float ebs = tb / bn;
        float y2  = ebs * ebs * bn2;

        float x2 = 0.f, xy = 0.f;
#pragma unroll
        for (int k = 0; k < D; ++k) { x2 += mx[k] * mx[k]; xy += mx[k] * bs[k]; }
        xy *= ebs;

        float c1 = 1.0f + 2.0f * xy + y2;
        float c2 = 1.0f - x2;
        float dn3 = 1.0f / fmaxf(1.0f + 2.0f * xy + x2 * y2, F_EPS);

        float r[D];
        float s3 = 0.f;
#pragma unroll
        for (int k = 0; k < D; ++k) {
            float rv = (c1 * mx[k] + c2 * ebs * bs[k]) * dn3;
            r[k] = rv;
            s3 += rv * rv;
        }
        float nrm3 = sqrtf(s3);
        float fp = 1.0f;
        if (nrm3 > MAXNORM) fp = MAXNORM / fmaxf(nrm3, F_EPS);

        float4* orow = reinterpret_cast<float4*>(out) + (size_t)i * DQ;
#pragma unroll
        for (int q = 0; q < DQ; ++q) {
            float4 v;
            v.x = r[q * 4 + 0] * fp;
            v.y = r[q * 4 + 1] * fp;
            v.z = r[q * 4 + 2] * fp;
            v.w = r[q * 4 + 3] * fp;
            orow[q] = v;
        }
    }
}

extern "C" void kernel_launch(void* const* d_in, const int* in_sizes, int n_in,
                              void* d_out, int out_size, void* d_ws, size_t ws_size,
                              hipStream_t stream)
{
    const float* x      = (const float*)d_in[0];
    const float* h_init = (const float*)d_in[1];
    const float* edge_w = (const float*)d_in[2];
    const float* W      = (const float*)d_in[3];
    const float* bias   = (const float*)d_in[4];
    const int*   esrc   = (const int*)d_in[5];
    const int*   edst   = (const int*)d_in[6];
    float* out = (float*)d_out;

    int n = in_sizes[0] / D;
    int E = in_sizes[2];
    int nb = (n + SPAN - 1) >> SHIFT;

    // ws layout
    char* p = (char*)d_ws;
    float* gam    = (float*)p;             p += (size_t)n * 4;
    float* den    = (float*)p;             p += (size_t)n * 4;
    int*   ghist  = (int*)p;               p += (size_t)nb * 4;
    int*   gstart = (int*)p;               p += (size_t)(nb + 1) * 4;
    int*   gcur   = (int*)p;               p += (size_t)nb * 4;
    int*   starts = (int*)p;               p += (size_t)(n + 1) * 4;
    p = (char*)(((uintptr_t)p + 15) & ~(uintptr_t)15);   // align 16
    int2*  seg    = (int2*)p;              p += (size_t)E * 8;
    int2*  seg2   = (int2*)p;              p += (size_t)E * 8;
    size_t need1 = (size_t)(p - (char*)d_ws);
    // ybf aliases seg (dead after k_sortb); needs n*96 bytes <= E*8 when E >= 12n
    ushort4* ybf = (ushort4*)seg;
    bool ybf_fits = ((size_t)E * 8 >= (size_t)n * D * 2);

    k_gamma<<<(n + 255) / 256, 256, 0, stream>>>(x, gam, ghist, n, nb);

    bool shape_ok = (nb <= 1024) && (n < (1 << 24));
    if (shape_ok && ybf_fits && need1 <= ws_size) {
        int pb = (E + PCH - 1) / PCH;
        k_hist<<<pb, PTH, 0, stream>>>(edst, ghist, E, nb);
        k_scanb<<<1, 1024, 0, stream>>>(ghist, gstart, gcur, nb, E);
        k_part<<<pb, PTH, 0, stream>>>(esrc, edst, edge_w, gcur, seg, E, nb);
        k_sortb<<<nb, 256, 0, stream>>>(seg, gstart, starts, seg2, n, E);
        long long tot = (long long)n * DQ;
        int gg = (int)((tot + 255) / 256);
        k_prep<<<gg, 256, 0, stream>>>(x, gam, ybf, n);
        k_gather<<<gg, 256, 0, stream>>>(ybf, gam, starts, seg2, out, den, n, E);
    } else {
        k_init_atomic<<<(n + 255) / 256, 256, 0, stream>>>(den, out, n);
        long long tot = (long long)E * DQ;
        k_edge_atomic<<<(int)((tot + 255) / 256), 256, 0, stream>>>(x, gam, esrc, edst, edge_w, out, den, E);
    }

    k_node<<<(n + 255) / 256, 256, 0, stream>>>(out, den, h_init, W, bias, n);
}

// Round 9
// 148.727 us; speedup vs baseline: 1.1491x; 1.1491x over previous
//
#include <hip/hip_runtime.h>
#include <math.h>

#define D  48
#define DQ 12        // D/4
#define SPAN 128     // nodes per bucket
#define SHIFT 7      // log2(SPAN)
#define PCH  8192    // edges per hist/partition block
#define PTH  512     // threads for hist/part

constexpr float F_EPS   = 1e-15f;
constexpr float MAXNORM = 1.0f - 1e-5f;

__device__ __forceinline__ float artanh_c(float x) {
    x = fminf(x, 1.0f - 1e-7f);
    x = fmaxf(x, -1.0f + 1e-7f);
    return atanhf(x);
}

__device__ __forceinline__ float clampabs(float x) {
    return (x >= 0.0f) ? fmaxf(x, 1e-10f) : fminf(x, -1e-10f);
}

__device__ __forceinline__ unsigned short f2bf(float f) {
    unsigned u = __float_as_uint(f);
    u += 0x7FFFu + ((u >> 16) & 1u);
    return (unsigned short)(u >> 16);
}

__device__ __forceinline__ float bf2f(unsigned short u) {
    return __uint_as_float(((unsigned)u) << 16);
}

// ---------- per-node gamma + zero bucket histogram ----------
__global__ void k_gamma(const float* __restrict__ x, float* __restrict__ gam,
                        int* __restrict__ ghist, int n, int nb)
{
    int i = blockIdx.x * blockDim.x + threadIdx.x;
    if (i < nb) ghist[i] = 0;
    if (i >= n) return;
    const float4* xr = reinterpret_cast<const float4*>(x) + (size_t)i * DQ;
    float s = 0.0f;
#pragma unroll
    for (int q = 0; q < DQ; ++q) {
        float4 v = xr[q];
        s += v.x * v.x + v.y * v.y + v.z * v.z + v.w * v.w;
    }
    gam[i] = 2.0f / fmaxf(1.0f - s, F_EPS);
}

// ---------- bucket histogram (LDS-staged, unrolled) ----------
__global__ __launch_bounds__(PTH) void k_hist(const int* __restrict__ dst,
                                              int* __restrict__ ghist, int E, int nb)
{
    __shared__ int h[1024];
    int t = threadIdx.x;
    for (int i = t; i < 1024; i += PTH) h[i] = 0;
    __syncthreads();
    int base = blockIdx.x * PCH;
#pragma unroll 4
    for (int k = 0; k < PCH / PTH; ++k) {
        int i = base + k * PTH + t;
        if (i < E) {
            unsigned b = ((unsigned)dst[i]) >> SHIFT;
            if (b < 1024u) atomicAdd(&h[b], 1);
        }
    }
    __syncthreads();
    for (int i = t; i < nb; i += PTH) {
        int c = h[i];
        if (c) atomicAdd(&ghist[i], c);
    }
}

// ---------- exclusive scan of bucket counts (single block, nb <= 1024) ----------
__global__ __launch_bounds__(1024) void k_scanb(const int* __restrict__ ghist,
                                                int* __restrict__ gstart,
                                                int* __restrict__ gcur, int nb, int E)
{
    __shared__ int sh[1024];
    int t = threadIdx.x;
    int v = (t < nb) ? ghist[t] : 0;
    sh[t] = v;
    __syncthreads();
    for (int off = 1; off < 1024; off <<= 1) {
        int a = sh[t];
        int b = (t >= off) ? sh[t - off] : 0;
        __syncthreads();
        sh[t] = a + b;
        __syncthreads();
    }
    if (t < nb) { int s = sh[t] - v; gstart[t] = s; gcur[t] = s; }
    if (t == 0) gstart[nb] = E;
}

// ---------- partition: bucket-burst records with packed bf16 weights ----------
__global__ __launch_bounds__(PTH) void k_part(const int* __restrict__ src,
                                              const int* __restrict__ dst,
                                              const float* __restrict__ w,
                                              const float* __restrict__ gam,
                                              int* __restrict__ gcur,
                                              int2* __restrict__ seg, int E, int nb)
{
    __shared__ int hist[1024];
    __shared__ int base_[1024];
    __shared__ int lcur[1024];
    int t = threadIdx.x;
    for (int i = t; i < 1024; i += PTH) { hist[i] = 0; base_[i] = 0; lcur[i] = 0; }
    __syncthreads();
    int b0 = blockIdx.x * PCH;
#pragma unroll 4
    for (int k = 0; k < PCH / PTH; ++k) {
        int i = b0 + k * PTH + t;
        if (i < E) {
            unsigned b = ((unsigned)dst[i]) >> SHIFT;
            if (b < 1024u) atomicAdd(&hist[b], 1);
        }
    }
    __syncthreads();
    for (int i = t; i < nb; i += PTH) {
        int c = hist[i];
        if (c) base_[i] = atomicAdd(&gcur[i], c);
    }
    __syncthreads();
#pragma unroll 4
    for (int k = 0; k < PCH / PTH; ++k) {
        int i = b0 + k * PTH + t;
        if (i < E) {
            int d = dst[i];
            unsigned b = ((unsigned)d) >> SHIFT;
            if (b < 1024u) {
                int s = src[i];
                float wv = w[i];
                float g  = gam[s];                      // hot 400KB array
                unsigned short wb  = f2bf(wv);
                unsigned short wdb = f2bf(fabsf(wv) * (g - 1.0f));
                int pos = base_[b] + atomicAdd(&lcur[b], 1);
                if (pos >= 0 && pos < E) {
                    int2 r;
                    r.x = ((d & (SPAN - 1)) << 24) | (s & 0xFFFFFF);
                    r.y = ((unsigned)wb << 16) | wdb;
                    seg[pos] = r;
                }
            }
        }
    }
}

// ---------- per-bucket LDS counting sort -> exact per-node order + starts ----------
__global__ __launch_bounds__(256) void k_sortb(
    const int2* __restrict__ seg, const int* __restrict__ gstart,
    int* __restrict__ starts, int2* __restrict__ seg2, int n, int E)
{
    __shared__ int hist[SPAN];
    __shared__ int sb[SPAN];
    __shared__ int cur[SPAN];
    int b = blockIdx.x;
    int t = threadIdx.x;
    if (b == 0 && t == 0) starts[n] = E;
    int segL = gstart[b], segR = gstart[b + 1];
    if (segL < 0) segL = 0;
    if (segR > E) segR = E;
    if (t < SPAN) hist[t] = 0;
    __syncthreads();
    {
        int j = segL + t;
        for (; j + 768 < segR; j += 1024) {
            unsigned d0 = ((unsigned)seg[j      ].x) >> 24;
            unsigned d1 = ((unsigned)seg[j + 256].x) >> 24;
            unsigned d2 = ((unsigned)seg[j + 512].x) >> 24;
            unsigned d3 = ((unsigned)seg[j + 768].x) >> 24;
            atomicAdd(&hist[d0], 1);
            atomicAdd(&hist[d1], 1);
            atomicAdd(&hist[d2], 1);
            atomicAdd(&hist[d3], 1);
        }
        for (; j < segR; j += 256) {
            unsigned dl = ((unsigned)seg[j].x) >> 24;
            atomicAdd(&hist[dl], 1);
        }
    }
    __syncthreads();
    if (t < SPAN) sb[t] = hist[t];
    __syncthreads();
    for (int off = 1; off < SPAN; off <<= 1) {
        int a = 0;
        if (t < SPAN) { a = sb[t]; if (t >= off) a += sb[t - off]; }
        __syncthreads();
        if (t < SPAN) sb[t] = a;
        __syncthreads();
    }
    if (t < SPAN) {
        int ls = sb[t] - hist[t];
        cur[t] = segL + ls;
        int node = b * SPAN + t;
        if (node < n) starts[node] = segL + ls;
    }
    __syncthreads();
    {
        int j = segL + t;
        for (; j + 768 < segR; j += 1024) {
            int2 r0 = seg[j      ];
            int2 r1 = seg[j + 256];
            int2 r2 = seg[j + 512];
            int2 r3 = seg[j + 768];
            int p0 = atomicAdd(&cur[((unsigned)r0.x) >> 24], 1);
            int p1 = atomicAdd(&cur[((unsigned)r1.x) >> 24], 1);
            int p2 = atomicAdd(&cur[((unsigned)r2.x) >> 24], 1);
            int p3 = atomicAdd(&cur[((unsigned)r3.x) >> 24], 1);
            if (p0 >= 0 && p0 < E) seg2[p0] = make_int2(r0.x & 0xFFFFFF, r0.y);
            if (p1 >= 0 && p1 < E) seg2[p1] = make_int2(r1.x & 0xFFFFFF, r1.y);
            if (p2 >= 0 && p2 < E) seg2[p2] = make_int2(r2.x & 0xFFFFFF, r2.y);
            if (p3 >= 0 && p3 < E) seg2[p3] = make_int2(r3.x & 0xFFFFFF, r3.y);
        }
        for (; j < segR; j += 256) {
            int2 r = seg[j];
            int pos = atomicAdd(&cur[((unsigned)r.x) >> 24], 1);
            if (pos >= 0 && pos < E) seg2[pos] = make_int2(r.x & 0xFFFFFF, r.y);
        }
    }
}

// ---------- precompute ybf[s] = bf16(gam[s] * x[s]) into dead seg buffer ----------
__global__ __launch_bounds__(256) void k_prep(const float* __restrict__ x,
                                              const float* __restrict__ gam,
                                              ushort4* __restrict__ ybf, int n)
{
    long long t = (long long)blockIdx.x * blockDim.x + threadIdx.x;
    int node = (int)(t / DQ);
    if (node >= n) return;
    int part = (int)(t % DQ);
    float g = gam[node];
    float4 v = reinterpret_cast<const float4*>(x)[(size_t)node * DQ + part];
    ushort4 o;
    o.x = f2bf(v.x * g);
    o.y = f2bf(v.y * g);
    o.z = f2bf(v.z * g);
    o.w = f2bf(v.w * g);
    ybf[(size_t)node * DQ + part] = o;
}

// ---------- gather: 12 lanes/node, single random stream, 4-wide pipeline ----------
__global__ __launch_bounds__(256) void k_gather(
    const ushort4* __restrict__ ybf,
    const int* __restrict__ starts,
    const int2* __restrict__ srec,
    float* __restrict__ num, float* __restrict__ den, int n, int E)
{
    long long t = (long long)blockIdx.x * blockDim.x + threadIdx.x;
    int node = (int)(t / DQ);
    if (node >= n) return;
    int part = (int)(t % DQ);
    int j0 = starts[node], j1 = starts[node + 1];
    if (j0 < 0) j0 = 0;
    if (j1 > E) j1 = E;
    float4 acc = make_float4(0.f, 0.f, 0.f, 0.f);
    float dacc = 0.f;
    int j = j0;
    for (; j + 3 < j1; j += 4) {
        int2 r0 = srec[j];
        int2 r1 = srec[j + 1];
        int2 r2 = srec[j + 2];
        int2 r3 = srec[j + 3];
        ushort4 a0 = ybf[(size_t)(r0.x) * DQ + part];
        ushort4 a1 = ybf[(size_t)(r1.x) * DQ + part];
        ushort4 a2 = ybf[(size_t)(r2.x) * DQ + part];
        ushort4 a3 = ybf[(size_t)(r3.x) * DQ + part];
        float w0 = bf2f((unsigned short)(((unsigned)r0.y) >> 16));
        float w1 = bf2f((unsigned short)(((unsigned)r1.y) >> 16));
        float w2 = bf2f((unsigned short)(((unsigned)r2.y) >> 16));
        float w3 = bf2f((unsigned short)(((unsigned)r3.y) >> 16));
        acc.x = fmaf(w0, bf2f(a0.x), acc.x);
        acc.y = fmaf(w0, bf2f(a0.y), acc.y);
        acc.z = fmaf(w0, bf2f(a0.z), acc.z);
        acc.w = fmaf(w0, bf2f(a0.w), acc.w);
        acc.x = fmaf(w1, bf2f(a1.x), acc.x);
        acc.y = fmaf(w1, bf2f(a1.y), acc.y);
        acc.z = fmaf(w1, bf2f(a1.z), acc.z);
        acc.w = fmaf(w1, bf2f(a1.w), acc.w);
        acc.x = fmaf(w2, bf2f(a2.x), acc.x);
        acc.y = fmaf(w2, bf2f(a2.y), acc.y);
        acc.z = fmaf(w2, bf2f(a2.z), acc.z);
        acc.w = fmaf(w2, bf2f(a2.w), acc.w);
        acc.x = fmaf(w3, bf2f(a3.x), acc.x);
        acc.y = fmaf(w3, bf2f(a3.y), acc.y);
        acc.z = fmaf(w3, bf2f(a3.z), acc.z);
        acc.w = fmaf(w3, bf2f(a3.w), acc.w);
        dacc += bf2f((unsigned short)(((unsigned)r0.y) & 0xFFFF))
              + bf2f((unsigned short)(((unsigned)r1.y) & 0xFFFF))
              + bf2f((unsigned short)(((unsigned)r2.y) & 0xFFFF))
              + bf2f((unsigned short)(((unsigned)r3.y) & 0xFFFF));
    }
    for (; j < j1; ++j) {
        int2 r0 = srec[j];
        ushort4 a0 = ybf[(size_t)(r0.x) * DQ + part];
        float w0 = bf2f((unsigned short)(((unsigned)r0.y) >> 16));
        acc.x = fmaf(w0, bf2f(a0.x), acc.x);
        acc.y = fmaf(w0, bf2f(a0.y), acc.y);
        acc.z = fmaf(w0, bf2f(a0.z), acc.z);
        acc.w = fmaf(w0, bf2f(a0.w), acc.w);
        dacc += bf2f((unsigned short)(((unsigned)r0.y) & 0xFFFF));
    }
    reinterpret_cast<float4*>(num)[(size_t)node * DQ + part] = acc;
    if (part == 0) den[node] = dacc;
}

// ---------- fallback: atomic edge scatter ----------
__global__ void k_init_atomic(float* __restrict__ den, float* __restrict__ num, int n)
{
    int i = blockIdx.x * blockDim.x + threadIdx.x;
    if (i >= n) return;
    den[i] = 0.0f;
    float4* nr = reinterpret_cast<float4*>(num) + (size_t)i * DQ;
    float4 z = make_float4(0.f, 0.f, 0.f, 0.f);
#pragma unroll
    for (int q = 0; q < DQ; ++q) nr[q] = z;
}

__global__ void k_edge_atomic(const float* __restrict__ x, const float* __restrict__ gam,
                              const int* __restrict__ src, const int* __restrict__ dst,
                              const float* __restrict__ w,
                              float* __restrict__ num, float* __restrict__ den, int E)
{
    long long t = (long long)blockIdx.x * blockDim.x + threadIdx.x;
    int e = (int)(t / DQ);
    if (e >= E) return;
    int part = (int)(t % DQ);
    int s = src[e];
    int d = dst[e];
    float we = w[e];
    float g  = gam[s];
    float4 xv = reinterpret_cast<const float4*>(x)[(size_t)s * DQ + part];
    float c = we * g;
    float* np_ = num + (size_t)d * D + part * 4;
    atomicAdd(np_ + 0, c * xv.x);
    atomicAdd(np_ + 1, c * xv.y);
    atomicAdd(np_ + 2, c * xv.z);
    atomicAdd(np_ + 3, c * xv.w);
    if (part == 0) atomicAdd(den + d, fabsf(we) * (g - 1.0f));
}

// mobius_scalar_mul(0.5, v) followed by _project, in place.
__device__ __forceinline__ void half_mul_project(float* v)
{
    float s = 0.f;
#pragma unroll
    for (int k = 0; k < D; ++k) s += v[k] * v[k];
    float nrm = sqrtf(s);
    float ncl = fmaxf(nrm, F_EPS);
    float t   = tanhf(0.5f * artanh_c(ncl));
    float sc  = t / ncl;
    float rn  = nrm * sc;
    if (rn > MAXNORM) sc *= MAXNORM / fmaxf(rn, F_EPS);
#pragma unroll
    for (int k = 0; k < D; ++k) v[k] *= sc;
}

__global__ __launch_bounds__(256) void k_node(
    float* __restrict__ out,
    const float* __restrict__ den,
    const float* __restrict__ h_init,
    const float* __restrict__ Wm,
    const float* __restrict__ bias, int n)
{
    __shared__ float Ws[D * D];
    __shared__ float bs[D];
    for (int k = threadIdx.x; k < D * D; k += blockDim.x) Ws[k] = Wm[k];
    if (threadIdx.x < D) bs[threadIdx.x] = bias[threadIdx.x];
    __syncthreads();

    int i = blockIdx.x * blockDim.x + threadIdx.x;
    if (i >= n) return;

    float a[D];
    {
        const float4* nr = reinterpret_cast<const float4*>(out) + (size_t)i * DQ;
        float dinv = 1.0f / clampabs(den[i]);
#pragma unroll
        for (int q = 0; q < DQ; ++q) {
            float4 v = nr[q];
            a[q * 4 + 0] = v.x * dinv;
            a[q * 4 + 1] = v.y * dinv;
            a[q * 4 + 2] = v.z * dinv;
            a[q * 4 + 3] = v.w * dinv;
        }
    }
    half_mul_project(a);

    {
        float b[D];
        const float4* hr = reinterpret_cast<const float4*>(h_init) + (size_t)i * DQ;
#pragma unroll
        for (int q = 0; q < DQ; ++q) {
            float4 v = hr[q];
            b[q * 4 + 0] = v.x; b[q * 4 + 1] = v.y;
            b[q * 4 + 2] = v.z; b[q * 4 + 3] = v.w;
        }
        float sa = 0.f, sb = 0.f;
#pragma unroll
        for (int k = 0; k < D; ++k) { sa += a[k] * a[k]; sb += b[k] * b[k]; }
        float ga = 2.0f / fmaxf(1.0f - sa, F_EPS);
        float gb = 2.0f / fmaxf(1.0f - sb, F_EPS);
        const float wa = 0.9f, wb = 0.1f;
        float dinv = 1.0f / clampabs(wa * (ga - 1.0f) + wb * (gb - 1.0f));
        float ca = wa * ga * dinv, cb = wb * gb * dinv;
#pragma unroll
        for (int k = 0; k < D; ++k) a[k] = ca * a[k] + cb * b[k];
        half_mul_project(a);
    }

    float mx[D];
    {
        float sa2 = 0.f;
#pragma unroll
        for (int k = 0; k < D; ++k) sa2 += a[k] * a[k];
        float xn = fmaxf(sqrtf(sa2), F_EPS);
        float smx = 0.f;
        for (int j = 0; j < D; ++j) {
            float acc = 0.f;
#pragma unroll
            for (int k = 0; k < D; ++k) acc = fmaf(Ws[j * D + k], a[k], acc);
            mx[j] = acc;
            smx += acc * acc;
        }
        float mxnr = sqrtf(smx);
        float mxn = fmaxf(mxnr, F_EPS);
        float tt = tanhf((mxn / xn) * artanh_c(xn));
        float sc = tt / mxn;
        float rn = mxnr * sc;
        if (rn > MAXNORM) sc *= MAXNORM / fmaxf(rn, F_EPS);
#pragma unroll
        for (int j = 0; j < D; ++j) mx[j] *= sc;
    }

    {
        float bn2 = 0.f;
#pragma unroll
        for (int k = 0; k < D; ++k) bn2 += bs[k] * bs[k];
        float bn  = fmaxf(sqrtf(bn2), F_EPS);
        float tb  = tanhf(bn);
        float ebs = tb / bn;
        float y2  = ebs * ebs * bn2;

        float x2 = 0.f, xy = 0.f;
#pragma unroll
        for (int k = 0; k < D; ++k) { x2 += mx[k] * mx[k]; xy += mx[k] * bs[k]; }
        xy *= ebs;

        float c1 = 1.0f + 2.0f * xy + y2;
        float c2 = 1.0f - x2;
        float dn3 = 1.0f / fmaxf(1.0f + 2.0f * xy + x2 * y2, F_EPS);

        float r[D];
        float s3 = 0.f;
#pragma unroll
        for (int k = 0; k < D; ++k) {
            float rv = (c1 * mx[k] + c2 * ebs * bs[k]) * dn3;
            r[k] = rv;
            s3 += rv * rv;
        }
        float nrm3 = sqrtf(s3);
        float fp = 1.0f;
        if (nrm3 > MAXNORM) fp = MAXNORM / fmaxf(nrm3, F_EPS);

        float4* orow = reinterpret_cast<float4*>(out) + (size_t)i * DQ;
#pragma unroll
        for (int q = 0; q < DQ; ++q) {
            float4 v;
            v.x = r[q * 4 + 0] * fp;
            v.y = r[q * 4 + 1] * fp;
            v.z = r[q * 4 + 2] * fp;
            v.w = r[q * 4 + 3] * fp;
            orow[q] = v;
        }
    }
}

extern "C" void kernel_launch(void* const* d_in, const int* in_sizes, int n_in,
                              void* d_out, int out_size, void* d_ws, size_t ws_size,
                              hipStream_t stream)
{
    const float* x      = (const float*)d_in[0];
    const float* h_init = (const float*)d_in[1];
    const float* edge_w = (const float*)d_in[2];
    const float* W      = (const float*)d_in[3];
    const float* bias   = (const float*)d_in[4];
    const int*   esrc   = (const int*)d_in[5];
    const int*   edst   = (const int*)d_in[6];
    float* out = (float*)d_out;

    int n = in_sizes[0] / D;
    int E = in_sizes[2];
    int nb = (n + SPAN - 1) >> SHIFT;

    // ws layout
    char* p = (char*)d_ws;
    float* gam    = (float*)p;             p += (size_t)n * 4;
    float* den    = (float*)p;             p += (size_t)n * 4;
    int*   ghist  = (int*)p;               p += (size_t)nb * 4;
    int*   gstart = (int*)p;               p += (size_t)(nb + 1) * 4;
    int*   gcur   = (int*)p;               p += (size_t)nb * 4;
    int*   starts = (int*)p;               p += (size_t)(n + 1) * 4;
    p = (char*)(((uintptr_t)p + 15) & ~(uintptr_t)15);   // align 16
    int2*  seg    = (int2*)p;              p += (size_t)E * 8;
    int2*  seg2   = (int2*)p;              p += (size_t)E * 8;
    size_t need1 = (size_t)(p - (char*)d_ws);
    // ybf aliases seg (dead after k_sortb)
    ushort4* ybf = (ushort4*)seg;
    bool ybf_fits = ((size_t)E * 8 >= (size_t)n * D * 2);

    k_gamma<<<(n + 255) / 256, 256, 0, stream>>>(x, gam, ghist, n, nb);

    bool shape_ok = (nb <= 1024) && (n < (1 << 24));
    if (shape_ok && ybf_fits && need1 <= ws_size) {
        int pb = (E + PCH - 1) / PCH;
        k_hist<<<pb, PTH, 0, stream>>>(edst, ghist, E, nb);
        k_scanb<<<1, 1024, 0, stream>>>(ghist, gstart, gcur, nb, E);
        k_part<<<pb, PTH, 0, stream>>>(esrc, edst, edge_w, gam, gcur, seg, E, nb);
        k_sortb<<<nb, 256, 0, stream>>>(seg, gstart, starts, seg2, n, E);
        long long tot = (long long)n * DQ;
        int gg = (int)((tot + 255) / 256);
        k_prep<<<gg, 256, 0, stream>>>(x, gam, ybf, n);
        k_gather<<<gg, 256, 0, stream>>>(ybf, starts, seg2, out, den, n, E);
    } else {
        k_init_atomic<<<(n + 255) / 256, 256, 0, stream>>>(den, out, n);
        long long tot = (long long)E * DQ;
        k_edge_atomic<<<(int)((tot + 255) / 256), 256, 0, stream>>>(x, gam, esrc, edst, edge_w, out, den, E);
    }

    k_node<<<(n + 255) / 256, 256, 0, stream>>>(out, den, h_init, W, bias, n);
}